// Round 1
// 172.021 us; speedup vs baseline: 1.0051x; 1.0051x over previous
//
#include <hip/hip_runtime.h>
#include <stdint.h>

#define B_   256
#define O_   128
#define D_   128
#define IN_  16384
#define NEGF (-9.0e15f)
#define TINYF 1.1754943508222875e-38f

// ---------------- threefry2x32 (JAX partitionable, 20 rounds) ----------------
__device__ __forceinline__ void tf2x32(uint32_t k0, uint32_t k1,
                                       uint32_t x0, uint32_t x1,
                                       uint32_t* o0, uint32_t* o1) {
  uint32_t k2 = k0 ^ k1 ^ 0x1BD11BDAu;
#define TFR(r) { x0 += x1; x1 = (x1 << (r)) | (x1 >> (32 - (r))); x1 ^= x0; }
  x0 += k0; x1 += k1;
  TFR(13) TFR(15) TFR(26) TFR(6)
  x0 += k1; x1 += k2 + 1u;
  TFR(17) TFR(29) TFR(16) TFR(24)
  x0 += k2; x1 += k0 + 2u;
  TFR(13) TFR(15) TFR(26) TFR(6)
  x0 += k0; x1 += k1 + 3u;
  TFR(17) TFR(29) TFR(16) TFR(24)
  x0 += k1; x1 += k2 + 4u;
  TFR(13) TFR(15) TFR(26) TFR(6)
  x0 += k2; x1 += k0 + 5u;
#undef TFR
  *o0 = x0; *o1 = x1;
}

__device__ __forceinline__ float gumbel_bits(uint32_t bits) {
  float f = __uint_as_float((bits >> 9) | 0x3f800000u) - 1.0f;  // [0,1)
  float u = fmaxf(TINYF, f + TINYF);
  return -logf(-logf(u));
}

__device__ __forceinline__ uint32_t mono32(float x) {
  int b = __float_as_int(x);
  return (uint32_t)b ^ ((uint32_t)(b >> 31) | 0x80000000u);
}

__device__ __forceinline__ float rl_f(float v, int l) {
  return __int_as_float(__builtin_amdgcn_readlane(__float_as_int(v), l));
}

// DPP helpers (identical trees to the rounds 5-10 passing trajectory)
#define DPPF(x, ctrl) __int_as_float(__builtin_amdgcn_mov_dpp( \
    __float_as_int(x), (ctrl), 0xf, 0xf, true))

__device__ __forceinline__ float wredmaxf(float x) {
  x = fmaxf(x, DPPF(x, 0xB1));
  x = fmaxf(x, DPPF(x, 0x4E));
  x = fmaxf(x, DPPF(x, 0x141));
  x = fmaxf(x, DPPF(x, 0x140));
  x = fmaxf(x, DPPF(x, 0x142));   // row_bcast15
  x = fmaxf(x, DPPF(x, 0x143));   // row_bcast31
  return rl_f(x, 63);
}
__device__ __forceinline__ float wredsumf(float x) {
  x = x + DPPF(x, 0xB1);
  x = x + DPPF(x, 0x4E);
  x = x + DPPF(x, 0x141);
  x = x + DPPF(x, 0x140);
  x = x + DPPF(x, 0x142);
  x = x + DPPF(x, 0x143);
  return rl_f(x, 63);
}

// ---------------- Kernel A: M[b][p][o] = <enc[b,p,:], W[o, p*D:(p+1)*D]> ----
// v2: occupancy-oriented restructure.
//   - tile = 64 o-rows x 128 b-rows per block; only the W half-tile lives in
//     LDS (64x132 = 33.8 KB) -> 2 blocks/CU (vs 132 KB -> 1 block/CU before),
//     8 waves/CU instead of 4, 2+ waves/SIMD for latency hiding.
//   - enc is streamed from global per dc-step: each ev load presents only 4
//     distinct 16B addresses per wave (16-lane broadcast), slice is
//     L2-resident; next step's ev is prefetched into regs under the FMAs.
//   - per-output FMA chain (acc0/acc1 over x,z / y,w, dc=0..124 step 4,
//     final acc0+acc1) is IDENTICAL to v1 -> M is bit-identical, sampler
//     decisions unchanged.
//   - gridDim.y packs {o-half, b-half}: linear ids of the 4 blocks sharing a
//     W tile differ by multiples of 128 -> same XCD (id%8) -> L2 reuse.
__global__ __launch_bounds__(256, 2) void build_M(
    const float* __restrict__ enc, const float* __restrict__ W,
    float* __restrict__ M) {
  const int p   = blockIdx.x;
  const int og0 = (blockIdx.y & 1) * 64;    // o-half base
  const int b0  = (blockIdx.y >> 1) * 128;  // b-half base
  const int t   = threadIdx.x;

  __shared__ float Ws[64 * 132];            // 33.8 KB

  // stage W half-tile: 64 rows x 128 floats (one-time, reg-staged)
  {
    const int rgrp = t >> 5;      // 0..7
    const int c16  = t & 31;      // col group
#pragma unroll
    for (int k = 0; k < 8; k++) {
      int row = k * 8 + rgrp;
      *(float4*)(Ws + row * 132 + c16 * 4) =
          *(const float4*)(W + (size_t)(og0 + row) * IN_ + p * D_ + c16 * 4);
    }
  }

  const int og = t & 15;   // o = og0 + og + 16*oi, oi in 0..3
  const int bg = t >> 4;   // b = b0  + bg + 16*bi, bi in 0..7

  const float* eb = enc + ((size_t)(b0 + bg) * O_ + p) * D_;
  const size_t bstride = (size_t)16 * O_ * D_;   // 16 b-rows apart

  // issue initial ev loads before the barrier (no LDS dependence)
  float4 ev[8], evn[8];
#pragma unroll
  for (int bi = 0; bi < 8; bi++)
    ev[bi] = *(const float4*)(eb + bi * bstride);

  __syncthreads();

  float acc0[8][4] = {}, acc1[8][4] = {};

  for (int dc = 0; dc < 128; dc += 4) {
    // prefetch next step's enc slice (hides L2 latency under the FMAs)
    if (dc < 124) {
#pragma unroll
      for (int bi = 0; bi < 8; bi++)
        evn[bi] = *(const float4*)(eb + bi * bstride + dc + 4);
    }
    float4 wv[4];
#pragma unroll
    for (int oi = 0; oi < 4; oi++)
      wv[oi] = *(const float4*)(Ws + (og + 16 * oi) * 132 + dc);
#pragma unroll
    for (int bi = 0; bi < 8; bi++)
#pragma unroll
      for (int oi = 0; oi < 4; oi++) {
        acc0[bi][oi] += ev[bi].x * wv[oi].x;
        acc1[bi][oi] += ev[bi].y * wv[oi].y;
        acc0[bi][oi] += ev[bi].z * wv[oi].z;
        acc1[bi][oi] += ev[bi].w * wv[oi].w;
      }
#pragma unroll
    for (int bi = 0; bi < 8; bi++) ev[bi] = evn[bi];
  }

#pragma unroll
  for (int bi = 0; bi < 8; bi++) {
    int b = b0 + bg + 16 * bi;
#pragma unroll
    for (int oi = 0; oi < 4; oi++) {
      int o = og0 + og + 16 * oi;
      M[((size_t)b * O_ + p) * O_ + o] = acc0[bi][oi] + acc1[bi][oi];
    }
  }
}

// ---------------- Kernel S: phase-separated sampler, 8 waves -----------------
__global__ __launch_bounds__(512, 1) void sampler(
    const float* __restrict__ M, const float* __restrict__ bias,
    const float* __restrict__ enc, const float* __restrict__ W, int use_M,
    float* __restrict__ out_pos, float* __restrict__ out_ls,
    float* __restrict__ out_err) {
  const int b = blockIdx.x;
  const int t = threadIdx.x;
  const int lane = t & 63;
  const int w = t >> 6;

  // interleaved: Mlds[p*128 + 2*k + h] = M[b][p][h*64+k]
  __shared__ float  Mlds[O_ * O_];          // 64 KB
  __shared__ float  Glds[O_ * O_];          // 64 KB, Glds[j*128+2*lane+h]
  __shared__ double snapPd[16 * 64 * 2];    // 16 KB
  __shared__ unsigned long long snapMk[16 * 2];
  __shared__ double lsSlot[16];
  __shared__ int    errSlot[16];
  __shared__ int    posb[O_];

  const float b1f = bias[lane], b2f = bias[lane + 64];

  // ---------- phase 0: stage M, conflict-free (coalesced dword loads,
  //            contiguous float2 LDS writes) ----------
  if (use_M) {
    const float* Mb = M + (size_t)b * O_ * O_;
    for (int p = w * 16; p < w * 16 + 16; p++) {
      float v1 = Mb[p * O_ + lane];
      float v2 = Mb[p * O_ + 64 + lane];
      float2 mv; mv.x = v1; mv.y = v2;
      *(float2*)&Mlds[p * O_ + 2 * lane] = mv;
    }
  } else {
    for (int idx = t; idx < O_ * O_; idx += 512) {
      int p = idx >> 7, o = idx & 127;
      const float* er = enc + ((size_t)b * O_ + p) * D_;
      const float* wr = W + (size_t)o * IN_ + p * D_;
      float s = 0.f;
      for (int d = 0; d < D_; d += 4) {
        float4 e4 = *(const float4*)(er + d);
        float4 w4 = *(const float4*)(wr + d);
        s += e4.x * w4.x + e4.y * w4.y + e4.z * w4.z + e4.w * w4.w;
      }
      Mlds[p * O_ + ((o & 63) << 1) + (o >> 6)] = s;
    }
  }
  __syncthreads();

  // ---------- phase 1: gumbels (waves 1-7) / Pd init (wave 0, fixed order) ---
  double Pd1 = 0.0, Pd2 = 0.0;
  if (w == 0) {
    for (int p = 0; p < O_; p++) {
      float2 mv = *(float2*)&Mlds[p * O_ + 2 * lane];
      Pd1 += (double)mv.x;
      Pd2 += (double)mv.y;
    }
  } else {
    for (int r = w - 1; r < O_; r += 7) {
      uint32_t k0j, k1j, w0, w1;
      tf2x32(0u, 42u, 0u, (uint32_t)r, &k0j, &k1j);
      uint32_t m1 = (uint32_t)(b * O_ + lane);
      tf2x32(k0j, k1j, 0u, m1, &w0, &w1);
      float g1 = gumbel_bits(w0 ^ w1);
      tf2x32(k0j, k1j, 0u, m1 + 64u, &w0, &w1);
      float g2 = gumbel_bits(w0 ^ w1);
      float2 gv; gv.x = g1; gv.y = g2;
      *(float2*)&Glds[r * O_ + 2 * lane] = gv;
    }
  }
  __syncthreads();

  // ---------- phase 2: serial chain, wave 0 alone (others parked) ----------
  if (w == 0) {
    __builtin_amdgcn_s_setprio(3);
    int mk1 = 0, mk2 = 0;
    unsigned long long bmk1 = 0ull, bmk2 = 0ull;
    float2 gcur = *(float2*)&Glds[2 * lane];

    for (int j = 0; j < O_; j++) {
      if ((j & 7) == 0) {        // snapshot state entering chunk j/8
        int c = j >> 3;
        double2 pv; pv.x = Pd1; pv.y = Pd2;
        *(double2*)&snapPd[(c * 64 + lane) * 2] = pv;
        if (lane == 0) { snapMk[c * 2] = bmk1; snapMk[c * 2 + 1] = bmk2; }
      }
      float pm1 = mk1 ? NEGF : ((float)Pd1 + b1f);
      float pm2 = mk2 ? NEGF : ((float)Pd2 + b2f);
      float2 gnext;
      if (j < O_ - 1) gnext = *(float2*)&Glds[(j + 1) * O_ + 2 * lane];

      // gumbel-max shortcut on z = pm + g; guard 1e-2 >> max fp divergence
      // (~1.3e-4) between z-ordering and the reference's y-ordering.
      float z1 = pm1 + gcur.x, z2 = pm2 + gcur.y;
      // combined top-2 (max, second) DPP tree; duplicate max => sm==zm => exact path
      float m = fmaxf(z1, z2), s = fminf(z1, z2);
#define MERGE(ctrl) { float om = DPPF(m, ctrl), os = DPPF(s, ctrl); \
      float nm = fmaxf(m, om); \
      float ns = fmaxf(fminf(m, om), fmaxf(s, os)); \
      m = nm; s = ns; }
      MERGE(0xB1) MERGE(0x4E) MERGE(0x141) MERGE(0x140) MERGE(0x142) MERGE(0x143)
#undef MERGE
      float zm = rl_f(m, 63), sm = rl_f(s, 63);

      int pos;
      if (zm - sm >= 1e-2f) {
        unsigned long long bal1 = __ballot(z1 == zm);
        unsigned long long bal2 = __ballot(z2 == zm);
        pos = bal1 ? (__ffsll(bal1) - 1) : (64 + __ffsll(bal2) - 1);
      } else {
        // exact reference op order (bit-identical to rounds 5-10)
        float mx = wredmaxf(fmaxf(pm1, pm2));
        float s1 = pm1 - mx, s2 = pm2 - mx;
        float ss = wredsumf(expf(s1) + expf(s2));
        float lse = logf(ss);
        float y1 = (s1 - lse) + gcur.x;
        float y2 = (s2 - lse) + gcur.y;
        float ym = wredmaxf(fmaxf(y1, y2));
        unsigned long long c1 = __ballot(y1 == ym);
        unsigned long long c2 = __ballot(y2 == ym);
        pos = c1 ? (__ffsll(c1) - 1) : (64 + __ffsll(c2) - 1);
      }

      if (lane == 0) posb[j] = pos;
      mk1 |= (lane == pos);
      mk2 |= (lane + 64 == pos);
      if (pos < 64) bmk1 |= 1ull << pos; else bmk2 |= 1ull << (pos - 64);
      float2 mv = *(float2*)&Mlds[pos * O_ + 2 * lane];
      Pd1 -= (double)mv.x;
      Pd2 -= (double)mv.y;
      gcur = gnext;
    }
    out_pos[(size_t)b * O_ + lane]      = (float)posb[127 - lane];
    out_pos[(size_t)b * O_ + 64 + lane] = (float)posb[63 - lane];
  }
  __syncthreads();

  // ---------- phase 3: rank/err/ls chunks, all 8 waves (2 each) -------------
  for (int c = w; c < 16; c += 8) {
    double2 pv = *(double2*)&snapPd[(c * 64 + lane) * 2];
    double P1 = pv.x, P2 = pv.y;
    unsigned long long bmk1 = snapMk[c * 2], bmk2 = snapMk[c * 2 + 1];
    double ls_acc = 0.0;
    int err_acc = 0;
    for (int j = 8 * c; j < 8 * c + 8; j++) {
      float p1 = (float)P1 + b1f;   // bit-identical to consumer's score
      float p2 = (float)P2 + b2f;
      // u64 keys: (mono<<7)|(127-idx); larger = better rank, idx tie-break
      uint64_t K1 = ((uint64_t)mono32(p1) << 7) | (uint32_t)(127 - lane);
      uint64_t K2 = ((uint64_t)mono32(p2) << 7) | (uint32_t)(63 - lane);
      // bitwise (j+1)-th-largest: 39-iteration binary search (exact)
      uint64_t P = 0;
#pragma unroll
      for (int bit = 38; bit >= 0; --bit) {
        uint64_t cand = P | (1ull << bit);
        int c1 = __popcll(__ballot(K1 >= cand));
        int c2 = __popcll(__ballot(K2 >= cand));
        if (c1 + c2 > j) P = cand;   // at least j+1 keys >= cand
      }
      unsigned long long t1 = __ballot(K1 == P), t2 = __ballot(K2 == P);
      int topl, msk;
      if (t1) { topl = __ffsll(t1) - 1; msk = (int)((bmk1 >> topl) & 1); }
      else    { topl = __ffsll(t2) - 1; msk = (int)((bmk2 >> topl) & 1); }
      err_acc += msk;

      // ls: exact reference op order / identical DPP trees
      float pm1 = ((bmk1 >> lane) & 1) ? NEGF : p1;
      float pm2 = ((bmk2 >> lane) & 1) ? NEGF : p2;
      float mx = wredmaxf(fmaxf(pm1, pm2));
      float ss = wredsumf(expf(pm1 - mx) + expf(pm2 - mx));
      float lse = logf(ss);
      int pos = posb[j];
      float psel = rl_f((pos < 64) ? p1 : p2, pos & 63);
      ls_acc += (double)((psel - mx) - lse);

      // advance state
      if (pos < 64) bmk1 |= 1ull << pos; else bmk2 |= 1ull << (pos - 64);
      float2 mv = *(float2*)&Mlds[pos * O_ + 2 * lane];
      P1 -= (double)mv.x;
      P2 -= (double)mv.y;
    }
    if (lane == 0) { lsSlot[c] = ls_acc; errSlot[c] = err_acc; }
  }
  __syncthreads();

  if (t == 0) {
    double lt = 0.0; int et = 0;
    for (int i = 0; i < 16; i++) { lt += lsSlot[i]; et += errSlot[i]; }
    out_ls[b]  = (float)lt;
    out_err[b] = (float)et;
  }
}

extern "C" void kernel_launch(void* const* d_in, const int* in_sizes, int n_in,
                              void* d_out, int out_size, void* d_ws, size_t ws_size,
                              hipStream_t stream) {
  const float* enc  = (const float*)d_in[0];
  const float* W    = (const float*)d_in[1];
  const float* bias = (const float*)d_in[2];
  float* out     = (float*)d_out;
  float* out_pos = out;                  // [256][128] positions (as f32)
  float* out_ls  = out + B_ * O_;        // [256]
  float* out_err = out + B_ * O_ + B_;   // [256]

  float* M = (float*)d_ws;
  const size_t needM = (size_t)B_ * O_ * O_ * sizeof(float);  // 16.7 MB
  int use_M = (ws_size >= needM) ? 1 : 0;

  if (use_M) build_M<<<dim3(O_, 4), 256, 0, stream>>>(enc, W, M);
  sampler<<<dim3(B_), 512, 0, stream>>>(M, bias, enc, W, use_M,
                                        out_pos, out_ls, out_err);
}

// Round 3
// 150.733 us; speedup vs baseline: 1.1471x; 1.1412x over previous
//
#include <hip/hip_runtime.h>
#include <stdint.h>

#define B_   256
#define O_   128
#define D_   128
#define IN_  16384
#define NEGF (-9.0e15f)
#define TINYF 1.1754943508222875e-38f

// ---------------- threefry2x32 (JAX partitionable, 20 rounds) ----------------
__device__ __forceinline__ void tf2x32(uint32_t k0, uint32_t k1,
                                       uint32_t x0, uint32_t x1,
                                       uint32_t* o0, uint32_t* o1) {
  uint32_t k2 = k0 ^ k1 ^ 0x1BD11BDAu;
#define TFR(r) { x0 += x1; x1 = (x1 << (r)) | (x1 >> (32 - (r))); x1 ^= x0; }
  x0 += k0; x1 += k1;
  TFR(13) TFR(15) TFR(26) TFR(6)
  x0 += k1; x1 += k2 + 1u;
  TFR(17) TFR(29) TFR(16) TFR(24)
  x0 += k2; x1 += k0 + 2u;
  TFR(13) TFR(15) TFR(26) TFR(6)
  x0 += k0; x1 += k1 + 3u;
  TFR(17) TFR(29) TFR(16) TFR(24)
  x0 += k1; x1 += k2 + 4u;
  TFR(13) TFR(15) TFR(26) TFR(6)
  x0 += k2; x1 += k0 + 5u;
#undef TFR
  *o0 = x0; *o1 = x1;
}

__device__ __forceinline__ float gumbel_bits(uint32_t bits) {
  float f = __uint_as_float((bits >> 9) | 0x3f800000u) - 1.0f;  // [0,1)
  float u = fmaxf(TINYF, f + TINYF);
  return -logf(-logf(u));
}

__device__ __forceinline__ uint32_t mono32(float x) {
  int b = __float_as_int(x);
  return (uint32_t)b ^ ((uint32_t)(b >> 31) | 0x80000000u);
}

__device__ __forceinline__ float rl_f(float v, int l) {
  return __int_as_float(__builtin_amdgcn_readlane(__float_as_int(v), l));
}

// DPP helpers (identical trees to the rounds 5-10 passing trajectory)
#define DPPF(x, ctrl) __int_as_float(__builtin_amdgcn_mov_dpp( \
    __float_as_int(x), (ctrl), 0xf, 0xf, true))

__device__ __forceinline__ float wredmaxf(float x) {
  x = fmaxf(x, DPPF(x, 0xB1));
  x = fmaxf(x, DPPF(x, 0x4E));
  x = fmaxf(x, DPPF(x, 0x141));
  x = fmaxf(x, DPPF(x, 0x140));
  x = fmaxf(x, DPPF(x, 0x142));   // row_bcast15
  x = fmaxf(x, DPPF(x, 0x143));   // row_bcast31
  return rl_f(x, 63);
}
__device__ __forceinline__ float wredsumf(float x) {
  x = x + DPPF(x, 0xB1);
  x = x + DPPF(x, 0x4E);
  x = x + DPPF(x, 0x141);
  x = x + DPPF(x, 0x140);
  x = x + DPPF(x, 0x142);
  x = x + DPPF(x, 0x143);
  return rl_f(x, 63);
}

// ---------------- Kernel A: M[b][p][o] = <enc[b,p,:], W[o, p*D:(p+1)*D]> ----
// (v2, validated in round 1: 64o x 128b tiles, W half-tile in LDS,
//  enc streamed+prefetch; per-output FMA chain bit-identical to v1.)
__global__ __launch_bounds__(256, 2) void build_M(
    const float* __restrict__ enc, const float* __restrict__ W,
    float* __restrict__ M) {
  const int p   = blockIdx.x;
  const int og0 = (blockIdx.y & 1) * 64;    // o-half base
  const int b0  = (blockIdx.y >> 1) * 128;  // b-half base
  const int t   = threadIdx.x;

  __shared__ float Ws[64 * 132];            // 33.8 KB

  {
    const int rgrp = t >> 5;
    const int c16  = t & 31;
#pragma unroll
    for (int k = 0; k < 8; k++) {
      int row = k * 8 + rgrp;
      *(float4*)(Ws + row * 132 + c16 * 4) =
          *(const float4*)(W + (size_t)(og0 + row) * IN_ + p * D_ + c16 * 4);
    }
  }

  const int og = t & 15;
  const int bg = t >> 4;

  const float* eb = enc + ((size_t)(b0 + bg) * O_ + p) * D_;
  const size_t bstride = (size_t)16 * O_ * D_;

  float4 ev[8], evn[8];
#pragma unroll
  for (int bi = 0; bi < 8; bi++)
    ev[bi] = *(const float4*)(eb + bi * bstride);

  __syncthreads();

  float acc0[8][4] = {}, acc1[8][4] = {};

  for (int dc = 0; dc < 128; dc += 4) {
    if (dc < 124) {
#pragma unroll
      for (int bi = 0; bi < 8; bi++)
        evn[bi] = *(const float4*)(eb + bi * bstride + dc + 4);
    }
    float4 wv[4];
#pragma unroll
    for (int oi = 0; oi < 4; oi++)
      wv[oi] = *(const float4*)(Ws + (og + 16 * oi) * 132 + dc);
#pragma unroll
    for (int bi = 0; bi < 8; bi++)
#pragma unroll
      for (int oi = 0; oi < 4; oi++) {
        acc0[bi][oi] += ev[bi].x * wv[oi].x;
        acc1[bi][oi] += ev[bi].y * wv[oi].y;
        acc0[bi][oi] += ev[bi].z * wv[oi].z;
        acc1[bi][oi] += ev[bi].w * wv[oi].w;
      }
#pragma unroll
    for (int bi = 0; bi < 8; bi++) ev[bi] = evn[bi];
  }

#pragma unroll
  for (int bi = 0; bi < 8; bi++) {
    int b = b0 + bg + 16 * bi;
#pragma unroll
    for (int oi = 0; oi < 4; oi++) {
      int o = og0 + og + 16 * oi;
      M[((size_t)b * O_ + p) * O_ + o] = acc0[bi][oi] + acc1[bi][oi];
    }
  }
}

// ---------------- Kernel S: pipelined sampler (hardened sync) ---------------
// Pipeline start: ALL flags zeroed, then __syncthreads() -> no init races.
// Every spin contains s_sleep(1) -> no priority livelock.
// DAG: stage{w0-3} -> stageDone ; gumbel{w4-7} -> flagG[c] ;
//      chain{w0} <- {stageDone, flagG} -> chainRel[c] ;
//      phase3{w1-7} <- chainRel. Acyclic, producers ungated -> terminates.
__global__ __launch_bounds__(512, 1) void sampler(
    const float* __restrict__ M, const float* __restrict__ bias,
    const float* __restrict__ enc, const float* __restrict__ W, int use_M,
    float* __restrict__ out_pos, float* __restrict__ out_ls,
    float* __restrict__ out_err) {
  const int b = blockIdx.x;
  const int t = threadIdx.x;
  const int lane = t & 63;
  const int w = t >> 6;

  // interleaved: Mlds[p*128 + 2*k + h] = M[b][p][h*64+k]
  __shared__ float  Mlds[O_ * O_];          // 64 KB
  __shared__ float  Glds[O_ * O_];          // 64 KB, Glds[j*128+2*lane+h]
  __shared__ double snapPd[16 * 64 * 2];    // 16 KB
  __shared__ unsigned long long snapMk[16 * 2];
  __shared__ double lsSlot[16];
  __shared__ int    errSlot[16];
  __shared__ int    posb[O_];
  __shared__ int    flagG[16];              // gumbel chunk ready
  __shared__ int    chainRel[16];           // chain chunk released
  __shared__ int    stageDone;              // staging waves done count

  volatile int* vFlagG = flagG;
  volatile int* vRel   = chainRel;
  volatile int* vSD    = &stageDone;

  const float b1f = bias[lane], b2f = bias[lane + 64];

  // ---------- flag init + pipeline start barrier (race-free) ----------
  if (t < 16) { flagG[t] = 0; chainRel[t] = 0; }
  if (t == 16) stageDone = 0;
  __syncthreads();

  // ---------- staging ----------
  if (!use_M) {
    // fallback (uniform branch): all waves compute Mlds, then barrier.
    for (int idx = t; idx < O_ * O_; idx += 512) {
      int p = idx >> 7, o = idx & 127;
      const float* er = enc + ((size_t)b * O_ + p) * D_;
      const float* wr = W + (size_t)o * IN_ + p * D_;
      float s = 0.f;
      for (int d = 0; d < D_; d += 4) {
        float4 e4 = *(const float4*)(er + d);
        float4 w4 = *(const float4*)(wr + d);
        s += e4.x * w4.x + e4.y * w4.y + e4.z * w4.z + e4.w * w4.w;
      }
      Mlds[p * O_ + ((o & 63) << 1) + (o >> 6)] = s;
    }
    __syncthreads();
    if (t == 0) *vSD = 4;
  } else if (w < 4) {
    const float* Mb = M + (size_t)b * O_ * O_;
    for (int p = w * 32; p < w * 32 + 32; p++) {
      float v1 = Mb[p * O_ + lane];
      float v2 = Mb[p * O_ + 64 + lane];
      float2 mv; mv.x = v1; mv.y = v2;
      *(float2*)&Mlds[p * O_ + 2 * lane] = mv;
    }
    __threadfence_block();
    if (lane == 0) atomicAdd(&stageDone, 1);
  }

  // ---------- gumbel producers (waves 4-7), ungated ----------
  if (w >= 4) {
#pragma unroll 1
    for (int k = 0; k < 4; k++) {
      int c = (w - 4) + 4 * k;          // wave 4 owns chunk 0 (first needed)
      for (int r = 8 * c; r < 8 * c + 8; r++) {
        uint32_t k0j, k1j, w0, w1;
        tf2x32(0u, 42u, 0u, (uint32_t)r, &k0j, &k1j);
        uint32_t m1 = (uint32_t)(b * O_ + lane);
        tf2x32(k0j, k1j, 0u, m1, &w0, &w1);
        float g1 = gumbel_bits(w0 ^ w1);
        tf2x32(k0j, k1j, 0u, m1 + 64u, &w0, &w1);
        float g2 = gumbel_bits(w0 ^ w1);
        float2 gv; gv.x = g1; gv.y = g2;
        *(float2*)&Glds[r * O_ + 2 * lane] = gv;
      }
      __threadfence_block();
      if (lane == 0) vFlagG[c] = 1;
    }
  }

  // ---------- wave 0: Pd init + serial chain ----------
  if (w == 0) {
    __builtin_amdgcn_s_setprio(3);
    while (*vSD < 4) __builtin_amdgcn_s_sleep(1);
    __threadfence_block();

    double Pd1 = 0.0, Pd2 = 0.0;
    for (int p = 0; p < O_; p++) {
      float2 mv = *(float2*)&Mlds[p * O_ + 2 * lane];
      Pd1 += (double)mv.x;
      Pd2 += (double)mv.y;
    }

    int mk1 = 0, mk2 = 0;
    unsigned long long bmk1 = 0ull, bmk2 = 0ull;
    while (vFlagG[0] == 0) __builtin_amdgcn_s_sleep(1);
    __threadfence_block();
    float2 gcur = *(float2*)&Glds[2 * lane];

    for (int j = 0; j < O_; j++) {
      if ((j & 7) == 0) {
        int c = j >> 3;
        if (c < 15) {                   // gate next chunk (covers gnext
          while (vFlagG[c + 1] == 0) __builtin_amdgcn_s_sleep(1);
          __threadfence_block();        //  crossing at j = 8c+7)
        }
        double2 pv; pv.x = Pd1; pv.y = Pd2;
        *(double2*)&snapPd[(c * 64 + lane) * 2] = pv;
        if (lane == 0) { snapMk[c * 2] = bmk1; snapMk[c * 2 + 1] = bmk2; }
      }
      float pm1 = mk1 ? NEGF : ((float)Pd1 + b1f);
      float pm2 = mk2 ? NEGF : ((float)Pd2 + b2f);
      float2 gnext;
      if (j < O_ - 1) gnext = *(float2*)&Glds[(j + 1) * O_ + 2 * lane];

      // gumbel-max shortcut: max-only DPP tree + popcount guard.
      // (unique lane above zm-1e-2 => gap >= 1e-2 => subset of the validated
      //  zm-sm>=1e-2 shortcut; borderline cases fall to the exact path.)
      float z1 = pm1 + gcur.x, z2 = pm2 + gcur.y;
      float m = fmaxf(z1, z2);
      m = fmaxf(m, DPPF(m, 0xB1));
      m = fmaxf(m, DPPF(m, 0x4E));
      m = fmaxf(m, DPPF(m, 0x141));
      m = fmaxf(m, DPPF(m, 0x140));
      m = fmaxf(m, DPPF(m, 0x142));
      m = fmaxf(m, DPPF(m, 0x143));
      float zm = rl_f(m, 63);
      float thr = zm - 1e-2f;
      unsigned long long n1 = __ballot(z1 > thr);
      unsigned long long n2 = __ballot(z2 > thr);

      int pos;
      if (__popcll(n1) + __popcll(n2) == 1) {
        pos = n1 ? (__ffsll(n1) - 1) : (64 + __ffsll(n2) - 1);
      } else {
        // exact reference op order (bit-identical to rounds 5-10)
        float mx = wredmaxf(fmaxf(pm1, pm2));
        float s1 = pm1 - mx, s2 = pm2 - mx;
        float ss = wredsumf(expf(s1) + expf(s2));
        float lse = logf(ss);
        float y1 = (s1 - lse) + gcur.x;
        float y2 = (s2 - lse) + gcur.y;
        float ym = wredmaxf(fmaxf(y1, y2));
        unsigned long long c1 = __ballot(y1 == ym);
        unsigned long long c2 = __ballot(y2 == ym);
        pos = c1 ? (__ffsll(c1) - 1) : (64 + __ffsll(c2) - 1);
      }

      if (lane == 0) posb[j] = pos;
      mk1 |= (lane == pos);
      mk2 |= (lane + 64 == pos);
      if (pos < 64) bmk1 |= 1ull << pos; else bmk2 |= 1ull << (pos - 64);
      float2 mv = *(float2*)&Mlds[pos * O_ + 2 * lane];
      Pd1 -= (double)mv.x;
      Pd2 -= (double)mv.y;
      if ((j & 7) == 7) {               // release chunk to phase-3 waves
        __threadfence_block();
        if (lane == 0) vRel[j >> 3] = 1;
      }
      gcur = gnext;
    }
    out_pos[(size_t)b * O_ + lane]      = (float)posb[127 - lane];
    out_pos[(size_t)b * O_ + 64 + lane] = (float)posb[63 - lane];
  }

  // ---------- phase 3: rank/err/ls chunks, concurrent with the chain -------
  if (w >= 1) {
    for (int c = w - 1; c < 16; c += 7) {
      while (vRel[c] == 0) __builtin_amdgcn_s_sleep(1);
      __threadfence_block();
      double2 pv = *(double2*)&snapPd[(c * 64 + lane) * 2];
      double P1 = pv.x, P2 = pv.y;
      unsigned long long bmk1 = snapMk[c * 2], bmk2 = snapMk[c * 2 + 1];
      double ls_acc = 0.0;
      int err_acc = 0;
      for (int j = 8 * c; j < 8 * c + 8; j++) {
        float p1 = (float)P1 + b1f;   // bit-identical to consumer's score
        float p2 = (float)P2 + b2f;
        // u64 keys: (mono<<7)|(127-idx); larger = better rank, idx tie-break
        uint64_t K1 = ((uint64_t)mono32(p1) << 7) | (uint32_t)(127 - lane);
        uint64_t K2 = ((uint64_t)mono32(p2) << 7) | (uint32_t)(63 - lane);
        // bitwise (j+1)-th-largest: 39-iteration binary search (exact)
        uint64_t P = 0;
#pragma unroll
        for (int bit = 38; bit >= 0; --bit) {
          uint64_t cand = P | (1ull << bit);
          int c1 = __popcll(__ballot(K1 >= cand));
          int c2 = __popcll(__ballot(K2 >= cand));
          if (c1 + c2 > j) P = cand;   // at least j+1 keys >= cand
        }
        unsigned long long t1 = __ballot(K1 == P), t2 = __ballot(K2 == P);
        int topl, msk;
        if (t1) { topl = __ffsll(t1) - 1; msk = (int)((bmk1 >> topl) & 1); }
        else    { topl = __ffsll(t2) - 1; msk = (int)((bmk2 >> topl) & 1); }
        err_acc += msk;

        // ls: exact reference op order / identical DPP trees
        float pm1 = ((bmk1 >> lane) & 1) ? NEGF : p1;
        float pm2 = ((bmk2 >> lane) & 1) ? NEGF : p2;
        float mx = wredmaxf(fmaxf(pm1, pm2));
        float ss = wredsumf(expf(pm1 - mx) + expf(pm2 - mx));
        float lse = logf(ss);
        int pos = posb[j];
        float psel = rl_f((pos < 64) ? p1 : p2, pos & 63);
        ls_acc += (double)((psel - mx) - lse);

        // advance state
        if (pos < 64) bmk1 |= 1ull << pos; else bmk2 |= 1ull << (pos - 64);
        float2 mv = *(float2*)&Mlds[pos * O_ + 2 * lane];
        P1 -= (double)mv.x;
        P2 -= (double)mv.y;
      }
      if (lane == 0) { lsSlot[c] = ls_acc; errSlot[c] = err_acc; }
    }
  }
  __syncthreads();

  if (t == 0) {
    double lt = 0.0; int et = 0;
    for (int i = 0; i < 16; i++) { lt += lsSlot[i]; et += errSlot[i]; }
    out_ls[b]  = (float)lt;
    out_err[b] = (float)et;
  }
}

extern "C" void kernel_launch(void* const* d_in, const int* in_sizes, int n_in,
                              void* d_out, int out_size, void* d_ws, size_t ws_size,
                              hipStream_t stream) {
  const float* enc  = (const float*)d_in[0];
  const float* W    = (const float*)d_in[1];
  const float* bias = (const float*)d_in[2];
  float* out     = (float*)d_out;
  float* out_pos = out;                  // [256][128] positions (as f32)
  float* out_ls  = out + B_ * O_;        // [256]
  float* out_err = out + B_ * O_ + B_;   // [256]

  float* M = (float*)d_ws;
  const size_t needM = (size_t)B_ * O_ * O_ * sizeof(float);  // 16.7 MB
  int use_M = (ws_size >= needM) ? 1 : 0;

  if (use_M) build_M<<<dim3(O_, 4), 256, 0, stream>>>(enc, W, M);
  sampler<<<dim3(B_), 512, 0, stream>>>(M, bias, enc, W, use_M,
                                        out_pos, out_ls, out_err);
}